// Round 3
// baseline (307.665 us; speedup 1.0000x reference)
//
#include <hip/hip_runtime.h>
#include <float.h>
#include <math.h>

// Problem constants
#define TT 4096          // tokens = B*S
#define HH 1024          // hidden
#define II 512           // expert ffn hidden
#define E_R 32
#define E_T 40
#define TOPK 6
#define SCALE_F 2.5f

typedef __bf16 bf16x8 __attribute__((ext_vector_type(8)));
typedef float f32x4 __attribute__((ext_vector_type(4)));

__device__ inline unsigned short f2bf(float f) {
  __bf16 h = (__bf16)f;                       // compiler emits v_cvt_pk_bf16_f32 for pairs
  return __builtin_bit_cast(unsigned short, h);
}

__device__ inline uint4 cvt8(float4 a, float4 b) {
  bf16x8 v;
  v[0] = (__bf16)a.x; v[1] = (__bf16)a.y; v[2] = (__bf16)a.z; v[3] = (__bf16)a.w;
  v[4] = (__bf16)b.x; v[5] = (__bf16)b.y; v[6] = (__bf16)b.z; v[7] = (__bf16)b.w;
  return __builtin_bit_cast(uint4, v);
}

// async global->LDS, 16B per lane, wave-uniform LDS base
__device__ inline void gload_lds16(const void* g, void* l) {
  __builtin_amdgcn_global_load_lds(
      (__attribute__((address_space(1))) void*)g,
      (__attribute__((address_space(3))) void*)l, 16, 0, 0);
}

// LDS tile helpers: [rows][64 bf16], row stride 128 B, XOR swizzle byte^=((row&7)<<4)
__device__ inline void lds_store16(unsigned short* base, int row, int c8, uint4 v) {
  int byte = (row * 128 + c8 * 16) ^ ((row & 7) << 4);
  *reinterpret_cast<uint4*>(reinterpret_cast<char*>(base) + byte) = v;
}
__device__ inline bf16x8 lds_frag(const unsigned short* base, int row, int kb) {
  int byte = (row * 128 + kb * 2) ^ ((row & 7) << 4);
  uint4 v = *reinterpret_cast<const uint4*>(reinterpret_cast<const char*>(base) + byte);
  return __builtin_bit_cast(bf16x8, v);
}

__device__ inline f32x4 mfma16(bf16x8 a, bf16x8 b, f32x4 c) {
  return __builtin_amdgcn_mfma_f32_16x16x32_bf16(a, b, c, 0, 0, 0);
}

// ---------------- kernel 1: convert x fp32 -> bf16 ----------------
__global__ void k_convert_x(const float* __restrict__ x, unsigned short* __restrict__ xb) {
  int i = blockIdx.x * 256 + threadIdx.x;          // one per 8 elements
  const float4* p = reinterpret_cast<const float4*>(x) + (size_t)i * 2;
  float4 a = p[0], b = p[1];
  reinterpret_cast<uint4*>(xb)[i] = cvt8(a, b);
}

// ---------------- kernel 2a: router logits (fp32 GEMV, wave per token) ----------------
__global__ __launch_bounds__(256) void k_logits(const float* __restrict__ x,
                                                const float* __restrict__ wcls,
                                                float* __restrict__ logits) {
  __shared__ float4 ws4[E_T * 64];                 // 40 experts x 256-float K-chunk = 40 KB
  const int tid = threadIdx.x;
  const int lane = tid & 63;
  const int wave = tid >> 6;
  const int token = blockIdx.x * 4 + wave;
  const float4* x4 = reinterpret_cast<const float4*>(x);
  const float4* w4 = reinterpret_cast<const float4*>(wcls);

  float acc[E_T];
  #pragma unroll
  for (int e = 0; e < E_T; ++e) acc[e] = 0.f;

  for (int c = 0; c < 4; ++c) {                    // 4 K-chunks of 256 floats
    if (c) __syncthreads();
    #pragma unroll
    for (int j = 0; j < 10; ++j) {                 // stage wcls chunk: 2560 float4 / 256 thr
      int v = tid + j * 256;
      int e = v >> 6, kq = v & 63;
      ws4[v] = w4[e * 256 + c * 64 + kq];
    }
    float4 xv = x4[(size_t)token * 256 + c * 64 + lane];
    __syncthreads();
    #pragma unroll
    for (int e = 0; e < E_T; ++e) {
      float4 w = ws4[e * 64 + lane];
      acc[e] += xv.x * w.x + xv.y * w.y + xv.z * w.z + xv.w * w.w;
    }
  }

  float mine = 0.f;
  #pragma unroll
  for (int e = 0; e < E_T; ++e) {
    float r = acc[e];
    #pragma unroll
    for (int o = 32; o; o >>= 1) r += __shfl_xor(r, o);
    if (lane == e) mine = r;
  }
  if (lane < E_T) logits[(size_t)token * E_T + lane] = mine;
}

// ---------------- kernel 2b: softmax + top-k, one thread per token ----------------
__global__ void k_topk(const float* __restrict__ logits, const float* __restrict__ bias,
                       float* __restrict__ zero_w, int* __restrict__ counts,
                       int* __restrict__ tok_list, float* __restrict__ wt_list) {
  int t = blockIdx.x * 64 + threadIdx.x;
  float l[E_T];
  const float4* lp = reinterpret_cast<const float4*>(logits + (size_t)t * E_T);
  #pragma unroll
  for (int j = 0; j < E_T / 4; ++j) {
    float4 v = lp[j];
    l[j * 4 + 0] = v.x; l[j * 4 + 1] = v.y; l[j * 4 + 2] = v.z; l[j * 4 + 3] = v.w;
  }
  float m = -FLT_MAX;
  #pragma unroll
  for (int e = 0; e < E_T; ++e) m = fmaxf(m, l[e]);
  float den = 0.f;
  #pragma unroll
  for (int e = 0; e < E_T; ++e) { l[e] = __expf(l[e] - m); den += l[e]; }
  float inv = 1.f / den;
  float sel[E_T];
  #pragma unroll
  for (int e = 0; e < E_T; ++e) { l[e] *= inv; sel[e] = l[e] + bias[e]; }

  unsigned long long used = 0ull;
  float zw = 0.f;
  for (int k = 0; k < TOPK; ++k) {
    float bv = -FLT_MAX; int bj = 0;
    #pragma unroll
    for (int e = 0; e < E_T; ++e) {
      float v = ((used >> e) & 1ull) ? -FLT_MAX : sel[e];
      if (v > bv) { bv = v; bj = e; }
    }
    used |= 1ull << bj;
    float wgt = (bv - bias[bj]) * SCALE_F;
    if (bj >= E_R) {
      zw += wgt;
    } else {
      int p = atomicAdd(&counts[bj], 1);
      tok_list[bj * TT + p] = t;
      wt_list[bj * TT + p] = wgt;
    }
  }
  zero_w[t] = zw;
}

// ---------------- kernel 3: prefix scan of counts ----------------
__global__ void k_scan(const int* __restrict__ counts, int* __restrict__ offsets) {
  if (threadIdx.x == 0) {
    int s = 0;
    for (int e = 0; e < E_R; ++e) { offsets[e] = s; s += counts[e]; }
    offsets[E_R] = s;
  }
}

// ---------------- kernel 4: out = x * zero_w ----------------
__global__ void k_init_out(const float* __restrict__ x, const float* __restrict__ zero_w,
                           float* __restrict__ out) {
  int i = blockIdx.x * 256 + threadIdx.x;          // one per 4 floats
  int t = i >> 8;
  float zw = zero_w[t];
  float4 v = reinterpret_cast<const float4*>(x)[i];
  v.x *= zw; v.y *= zw; v.z *= zw; v.w *= zw;
  reinterpret_cast<float4*>(out)[i] = v;
}

// ---------------- kernel 5: grouped GEMM1 + SiLU*up -> inter (bf16) ----------------
// m97-style: BM=128 token rows, 64 gate cols + matching 64 up cols, K=1024, 4 waves 2x2,
// wave output 64x32(gate)+64x32(up). A via global_load_lds (pre-swizzled source).
__global__ __launch_bounds__(256) void k_gemm1(
    const unsigned short* __restrict__ xb, const float* __restrict__ gup,
    const int* __restrict__ tok_list, const int* __restrict__ counts,
    const int* __restrict__ offsets, unsigned short* __restrict__ inter) {
  const int e = blockIdx.z;
  const int cnt = counts[e];
  const int row0 = blockIdx.y * 128;
  if (row0 >= cnt) return;
  const int n0 = blockIdx.x * 64;
  const int off = offsets[e];
  const int tid = threadIdx.x;
  const int lane = tid & 63;
  const int wave = tid >> 6;
  const int wr = wave >> 1, wc = wave & 1;

  __shared__ __align__(16) unsigned short lA[128 * 64];   // 16 KB
  __shared__ __align__(16) unsigned short lBg[64 * 64];   // 8 KB
  __shared__ __align__(16) unsigned short lBu[64 * 64];   // 8 KB
  __shared__ int toks[128];

  if (tid < 128) {
    int r = row0 + tid;
    toks[tid] = tok_list[e * TT + (r < cnt ? r : cnt - 1)];
  }
  __syncthreads();

  // per-lane A source element-offsets (pre-swizzled column chunk), 4 issues/wave
  size_t asrc[4];
  #pragma unroll
  for (int i = 0; i < 4; ++i) {
    int lrow = wave * 32 + i * 8 + (lane >> 3);
    asrc[i] = (size_t)toks[lrow] * HH + (((lane & 7) ^ (lrow & 7)) * 8);
  }
  // B row pointers (fp32), 2 chunk-stores per thread per matrix
  const float4* bgp[2]; const float4* bup[2];
  int brow[2], bc8[2];
  #pragma unroll
  for (int s = 0; s < 2; ++s) {
    int idx = tid + s * 256;
    brow[s] = idx >> 3; bc8[s] = idx & 7;
    bgp[s] = reinterpret_cast<const float4*>(gup + ((size_t)e * 1024 + n0 + brow[s]) * HH) + bc8[s] * 2;
    bup[s] = reinterpret_cast<const float4*>(gup + ((size_t)e * 1024 + 512 + n0 + brow[s]) * HH) + bc8[s] * 2;
  }

  f32x4 accg[4][2] = {}; f32x4 accu[4][2] = {};

  for (int k0 = 0; k0 < HH; k0 += 64) {
    int kq = k0 >> 2;                              // float4 index of k0
    #pragma unroll
    for (int i = 0; i < 4; ++i)
      gload_lds16(xb + asrc[i] + k0, lA + (wave * 32 + i * 8) * 64);
    #pragma unroll
    for (int s = 0; s < 2; ++s) {
      float4 ga = bgp[s][kq], gb = bgp[s][kq + 1];
      lds_store16(lBg, brow[s], bc8[s], cvt8(ga, gb));
      float4 ua = bup[s][kq], ub = bup[s][kq + 1];
      lds_store16(lBu, brow[s], bc8[s], cvt8(ua, ub));
    }
    __syncthreads();
    #pragma unroll
    for (int ks = 0; ks < 2; ++ks) {
      int kb = ks * 32 + ((lane >> 4) << 3);
      bf16x8 a[4], g[2], u[2];
      #pragma unroll
      for (int i = 0; i < 4; ++i) a[i] = lds_frag(lA, wr * 64 + i * 16 + (lane & 15), kb);
      #pragma unroll
      for (int j = 0; j < 2; ++j) {
        g[j] = lds_frag(lBg, wc * 32 + j * 16 + (lane & 15), kb);
        u[j] = lds_frag(lBu, wc * 32 + j * 16 + (lane & 15), kb);
      }
      #pragma unroll
      for (int i = 0; i < 4; ++i)
        #pragma unroll
        for (int j = 0; j < 2; ++j) {
          accg[i][j] = mfma16(a[i], g[j], accg[i][j]);
          accu[i][j] = mfma16(a[i], u[j], accu[i][j]);
        }
    }
    __syncthreads();
  }

  #pragma unroll
  for (int i = 0; i < 4; ++i)
    #pragma unroll
    for (int j = 0; j < 2; ++j)
      #pragma unroll
      for (int r = 0; r < 4; ++r) {
        int rloc = wr * 64 + i * 16 + ((lane >> 4) << 2) + r;
        int grow = row0 + rloc;
        if (grow < cnt) {
          int col = n0 + wc * 32 + j * 16 + (lane & 15);
          float gv = accg[i][j][r], uv = accu[i][j][r];
          float act = gv / (1.f + __expf(-gv)) * uv;
          inter[(size_t)(off + grow) * II + col] = f2bf(act);
        }
      }
}

// ---------------- kernel 6: grouped GEMM2, scatter-add into out ----------------
// BM=128 rows, BN=128 out cols, K=512, 4 waves 2x2, wave output 64x64.
__global__ __launch_bounds__(256) void k_gemm2(
    const unsigned short* __restrict__ inter, const float* __restrict__ dwn,
    const int* __restrict__ tok_list, const float* __restrict__ wt_list,
    const int* __restrict__ counts, const int* __restrict__ offsets,
    float* __restrict__ out) {
  const int e = blockIdx.z;
  const int cnt = counts[e];
  const int row0 = blockIdx.y * 128;
  if (row0 >= cnt) return;
  const int h0 = blockIdx.x * 128;
  const int off = offsets[e];
  const int tid = threadIdx.x;
  const int lane = tid & 63;
  const int wave = tid >> 6;
  const int wr = wave >> 1, wc = wave & 1;

  __shared__ __align__(16) unsigned short lA[128 * 64];   // 16 KB
  __shared__ __align__(16) unsigned short lB[128 * 64];   // 16 KB
  __shared__ int toks[128];
  __shared__ float wts[128];

  if (tid < 128) {
    int r = row0 + tid;
    int rc = r < cnt ? r : cnt - 1;
    toks[tid] = tok_list[e * TT + rc];
    wts[tid] = (r < cnt) ? wt_list[e * TT + rc] : 0.f;
  }
  __syncthreads();

  size_t asrc[4];
  #pragma unroll
  for (int i = 0; i < 4; ++i) {
    int lrow = wave * 32 + i * 8 + (lane >> 3);
    int rr = row0 + lrow; rr = rr < cnt ? rr : cnt - 1;
    asrc[i] = (size_t)(off + rr) * II + (((lane & 7) ^ (lrow & 7)) * 8);
  }
  const float4* bp[4];
  int brow[4], bc8[4];
  #pragma unroll
  for (int s = 0; s < 4; ++s) {
    int idx = tid + s * 256;
    brow[s] = idx >> 3; bc8[s] = idx & 7;
    bp[s] = reinterpret_cast<const float4*>(dwn + ((size_t)e * HH + h0 + brow[s]) * II) + bc8[s] * 2;
  }

  f32x4 acc[4][4] = {};

  for (int k0 = 0; k0 < II; k0 += 64) {
    int kq = k0 >> 2;
    #pragma unroll
    for (int i = 0; i < 4; ++i)
      gload_lds16(inter + asrc[i] + k0, lA + (wave * 32 + i * 8) * 64);
    #pragma unroll
    for (int s = 0; s < 4; ++s) {
      float4 a = bp[s][kq], b = bp[s][kq + 1];
      lds_store16(lB, brow[s], bc8[s], cvt8(a, b));
    }
    __syncthreads();
    #pragma unroll
    for (int ks = 0; ks < 2; ++ks) {
      int kb = ks * 32 + ((lane >> 4) << 3);
      bf16x8 a[4], b[4];
      #pragma unroll
      for (int i = 0; i < 4; ++i) a[i] = lds_frag(lA, wr * 64 + i * 16 + (lane & 15), kb);
      #pragma unroll
      for (int j = 0; j < 4; ++j) b[j] = lds_frag(lB, wc * 64 + j * 16 + (lane & 15), kb);
      #pragma unroll
      for (int i = 0; i < 4; ++i)
        #pragma unroll
        for (int j = 0; j < 4; ++j)
          acc[i][j] = mfma16(a[i], b[j], acc[i][j]);
    }
    __syncthreads();
  }

  #pragma unroll
  for (int i = 0; i < 4; ++i)
    #pragma unroll
    for (int j = 0; j < 4; ++j)
      #pragma unroll
      for (int r = 0; r < 4; ++r) {
        int rloc = wr * 64 + i * 16 + ((lane >> 4) << 2) + r;
        int grow = row0 + rloc;
        if (grow < cnt) {
          int h = h0 + wc * 64 + j * 16 + (lane & 15);
          unsafeAtomicAdd(&out[(size_t)toks[rloc] * HH + h], acc[i][j][r] * wts[rloc]);
        }
      }
}

// ---------------- ws layout ----------------
// xb      : TT*HH bf16          =  8,388,608 B   @ 0
// zero_w  : TT f32              =     16,384 B   @ 8,388,608
// counts  : 32 i32              =        128 B   @ 8,404,992
// offsets : 33 i32 (pad 256)    =        256 B   @ 8,405,120
// tok_list: 32*TT i32           =    524,288 B   @ 8,405,376
// wt_list : 32*TT f32           =    524,288 B   @ 8,929,664
// logits  : TT*E_T f32          =    655,360 B   @ 9,453,952
// inter   : 24576*II bf16       = 25,165,824 B   @ 10,109,312
// total ~= 35.3 MB

extern "C" void kernel_launch(void* const* d_in, const int* in_sizes, int n_in,
                              void* d_out, int out_size, void* d_ws, size_t ws_size,
                              hipStream_t stream) {
  const float* x    = (const float*)d_in[0];
  const float* wcls = (const float*)d_in[1];
  const float* bias = (const float*)d_in[2];
  const float* gup  = (const float*)d_in[3];
  const float* dwn  = (const float*)d_in[4];
  float* out = (float*)d_out;

  char* w = (char*)d_ws;
  unsigned short* xb   = (unsigned short*)(w + 0);
  float* zero_w        = (float*)(w + 8388608);
  int* counts          = (int*)(w + 8404992);
  int* offsets         = (int*)(w + 8405120);
  int* tok_list        = (int*)(w + 8405376);
  float* wt_list       = (float*)(w + 8929664);
  float* logits        = (float*)(w + 9453952);
  unsigned short* inter = (unsigned short*)(w + 10109312);

  hipMemsetAsync(counts, 0, E_R * sizeof(int), stream);
  k_convert_x<<<2048, 256, 0, stream>>>(x, xb);
  k_logits<<<1024, 256, 0, stream>>>(x, wcls, logits);
  k_topk<<<64, 64, 0, stream>>>(logits, bias, zero_w, counts, tok_list, wt_list);
  k_scan<<<1, 64, 0, stream>>>(counts, offsets);
  k_init_out<<<4096, 256, 0, stream>>>(x, zero_w, out);
  k_gemm1<<<dim3(8, 32, E_R), 256, 0, stream>>>(xb, gup, tok_list, counts, offsets, inter);
  k_gemm2<<<dim3(8, 32, E_R), 256, 0, stream>>>(inter, dwn, tok_list, wt_list, counts, offsets, out);
}

// Round 4
// 256.744 us; speedup vs baseline: 1.1983x; 1.1983x over previous
//
#include <hip/hip_runtime.h>
#include <float.h>
#include <math.h>

// Problem constants
#define TT 4096          // tokens = B*S
#define HH 1024          // hidden
#define II 512           // expert ffn hidden
#define E_R 32
#define E_T 40
#define TOPK 6
#define SCALE_F 2.5f
#define MAXTILES 224     // >= sum_e ceil(cnt_e/128); (24576+32*127)/128 = 223.75

typedef __bf16 bf16x8 __attribute__((ext_vector_type(8)));
typedef float f32x4 __attribute__((ext_vector_type(4)));

__device__ inline unsigned short f2bf(float f) {
  __bf16 h = (__bf16)f;
  return __builtin_bit_cast(unsigned short, h);
}

__device__ inline uint4 cvt8(float4 a, float4 b) {
  bf16x8 v;
  v[0] = (__bf16)a.x; v[1] = (__bf16)a.y; v[2] = (__bf16)a.z; v[3] = (__bf16)a.w;
  v[4] = (__bf16)b.x; v[5] = (__bf16)b.y; v[6] = (__bf16)b.z; v[7] = (__bf16)b.w;
  return __builtin_bit_cast(uint4, v);
}

// async global->LDS, 16B per lane, wave-uniform LDS base (linear dest)
__device__ inline void gload_lds16(const void* g, void* l) {
  __builtin_amdgcn_global_load_lds(
      (__attribute__((address_space(1))) void*)g,
      (__attribute__((address_space(3))) void*)l, 16, 0, 0);
}

// LDS tile: [rows][64 bf16], row stride 128 B, XOR swizzle byte^=((row&7)<<4).
// gload_lds path: LDS stays linear, SOURCE chunk is pre-XORed; read applies same XOR.
__device__ inline void lds_store16(unsigned short* base, int row, int c8, uint4 v) {
  int byte = (row * 128 + c8 * 16) ^ ((row & 7) << 4);
  *reinterpret_cast<uint4*>(reinterpret_cast<char*>(base) + byte) = v;
}
__device__ inline bf16x8 lds_frag(const unsigned short* base, int row, int kb) {
  int byte = (row * 128 + kb * 2) ^ ((row & 7) << 4);
  uint4 v = *reinterpret_cast<const uint4*>(reinterpret_cast<const char*>(base) + byte);
  return __builtin_bit_cast(bf16x8, v);
}

__device__ inline f32x4 mfma16(bf16x8 a, bf16x8 b, f32x4 c) {
  return __builtin_amdgcn_mfma_f32_16x16x32_bf16(a, b, c, 0, 0, 0);
}

// ---------------- kernel 1: convert x fp32 -> bf16 ----------------
__global__ void k_convert_x(const float* __restrict__ x, unsigned short* __restrict__ xb) {
  int i = blockIdx.x * 256 + threadIdx.x;
  const float4* p = reinterpret_cast<const float4*>(x) + (size_t)i * 2;
  float4 a = p[0], b = p[1];
  reinterpret_cast<uint4*>(xb)[i] = cvt8(a, b);
}

// ---------------- kernel 2a: router logits (fp32 GEMV, wave per token) ----------------
__global__ __launch_bounds__(256) void k_logits(const float* __restrict__ x,
                                                const float* __restrict__ wcls,
                                                float* __restrict__ logits) {
  __shared__ float4 ws4[E_T * 64];                 // 40 KB
  const int tid = threadIdx.x;
  const int lane = tid & 63;
  const int wave = tid >> 6;
  const int token = blockIdx.x * 4 + wave;
  const float4* x4 = reinterpret_cast<const float4*>(x);
  const float4* w4 = reinterpret_cast<const float4*>(wcls);

  float acc[E_T];
  #pragma unroll
  for (int e = 0; e < E_T; ++e) acc[e] = 0.f;

  for (int c = 0; c < 4; ++c) {
    if (c) __syncthreads();
    #pragma unroll
    for (int j = 0; j < 10; ++j) {
      int v = tid + j * 256;
      int e = v >> 6, kq = v & 63;
      ws4[v] = w4[e * 256 + c * 64 + kq];
    }
    float4 xv = x4[(size_t)token * 256 + c * 64 + lane];
    __syncthreads();
    #pragma unroll
    for (int e = 0; e < E_T; ++e) {
      float4 w = ws4[e * 64 + lane];
      acc[e] += xv.x * w.x + xv.y * w.y + xv.z * w.z + xv.w * w.w;
    }
  }

  float mine = 0.f;
  #pragma unroll
  for (int e = 0; e < E_T; ++e) {
    float r = acc[e];
    #pragma unroll
    for (int o = 32; o; o >>= 1) r += __shfl_xor(r, o);
    if (lane == e) mine = r;
  }
  if (lane < E_T) logits[(size_t)token * E_T + lane] = mine;
}

// ---------------- kernel 2b: softmax + top-k, one thread per token ----------------
__global__ void k_topk(const float* __restrict__ logits, const float* __restrict__ bias,
                       float* __restrict__ zero_w, int* __restrict__ counts,
                       int* __restrict__ tok_list, float* __restrict__ wt_list) {
  int t = blockIdx.x * 64 + threadIdx.x;
  float l[E_T];
  const float4* lp = reinterpret_cast<const float4*>(logits + (size_t)t * E_T);
  #pragma unroll
  for (int j = 0; j < E_T / 4; ++j) {
    float4 v = lp[j];
    l[j * 4 + 0] = v.x; l[j * 4 + 1] = v.y; l[j * 4 + 2] = v.z; l[j * 4 + 3] = v.w;
  }
  float m = -FLT_MAX;
  #pragma unroll
  for (int e = 0; e < E_T; ++e) m = fmaxf(m, l[e]);
  float den = 0.f;
  #pragma unroll
  for (int e = 0; e < E_T; ++e) { l[e] = __expf(l[e] - m); den += l[e]; }
  float inv = 1.f / den;
  float sel[E_T];
  #pragma unroll
  for (int e = 0; e < E_T; ++e) { l[e] *= inv; sel[e] = l[e] + bias[e]; }

  unsigned long long used = 0ull;
  float zw = 0.f;
  for (int k = 0; k < TOPK; ++k) {
    float bv = -FLT_MAX; int bj = 0;
    #pragma unroll
    for (int e = 0; e < E_T; ++e) {
      float v = ((used >> e) & 1ull) ? -FLT_MAX : sel[e];
      if (v > bv) { bv = v; bj = e; }
    }
    used |= 1ull << bj;
    float wgt = (bv - bias[bj]) * SCALE_F;
    if (bj >= E_R) {
      zw += wgt;
    } else {
      int p = atomicAdd(&counts[bj], 1);
      tok_list[bj * TT + p] = t;
      wt_list[bj * TT + p] = wgt;
    }
  }
  zero_w[t] = zw;
}

// ---------------- kernel 3: prefix scan + compact tile list ----------------
__global__ void k_scan(const int* __restrict__ counts, int* __restrict__ offsets,
                       int* __restrict__ tiles) {
  if (threadIdx.x == 0) {
    int s = 0, idx = 0;
    for (int e = 0; e < E_R; ++e) {
      offsets[e] = s;
      int c = counts[e];
      s += c;
      for (int r0 = 0; r0 < c; r0 += 128) tiles[1 + idx++] = (e << 16) | r0;
    }
    offsets[E_R] = s;
    tiles[0] = idx;
  }
}

// ---------------- kernel 4: out = x * zero_w ----------------
__global__ void k_init_out(const float* __restrict__ x, const float* __restrict__ zero_w,
                           float* __restrict__ out) {
  int i = blockIdx.x * 256 + threadIdx.x;
  int t = i >> 8;
  float zw = zero_w[t];
  float4 v = reinterpret_cast<const float4*>(x)[i];
  v.x *= zw; v.y *= zw; v.z *= zw; v.w *= zw;
  reinterpret_cast<float4*>(out)[i] = v;
}

// ---------------- kernel 5: grouped GEMM1 + SiLU*up -> inter (bf16) ----------------
// 512 thr / 8 waves. BM=128 rows, 64 gate + 64 up cols. Wave = 64 rows x (16g+16u):
// acc 8 f32x4 = 32 AGPR -> <=128 unified regs -> 16 waves/CU.
__global__ __launch_bounds__(512, 4) void k_gemm1(
    const unsigned short* __restrict__ xb, const float* __restrict__ gup,
    const int* __restrict__ tok_list, const int* __restrict__ counts,
    const int* __restrict__ offsets, const int* __restrict__ tiles,
    unsigned short* __restrict__ inter) {
  const int nt = tiles[0];
  if ((int)blockIdx.y >= nt) return;
  const int tv = tiles[1 + blockIdx.y];
  const int e = tv >> 16;
  const int row0 = tv & 0xffff;
  const int cnt = counts[e];
  const int off = offsets[e];
  const int n0 = blockIdx.x * 64;
  const int tid = threadIdx.x;
  const int lane = tid & 63;
  const int wave = tid >> 6;       // 0..7
  const int wr = wave >> 2;        // 0..1  M half
  const int wcol = wave & 3;       // 0..3  16-col slice

  __shared__ __align__(16) unsigned short lA[128 * 64];   // 16 KB
  __shared__ __align__(16) unsigned short lBg[64 * 64];   // 8 KB
  __shared__ __align__(16) unsigned short lBu[64 * 64];   // 8 KB
  __shared__ int toks[128];

  if (tid < 128) {
    int r = row0 + tid;
    toks[tid] = tok_list[e * TT + (r < cnt ? r : cnt - 1)];
  }
  __syncthreads();

  size_t asrc[2];
  #pragma unroll
  for (int i = 0; i < 2; ++i) {
    int lrow = wave * 16 + i * 8 + (lane >> 3);
    asrc[i] = (size_t)toks[lrow] * HH + (((lane & 7) ^ (lrow & 7)) * 8);
  }
  const int brow = tid >> 3, bc8 = tid & 7;      // 512 thr = 64 rows x 8 chunks
  const float4* bgp = reinterpret_cast<const float4*>(
      gup + ((size_t)e * 1024 + n0 + brow) * HH) + bc8 * 2;
  const float4* bup = reinterpret_cast<const float4*>(
      gup + ((size_t)e * 1024 + 512 + n0 + brow) * HH) + bc8 * 2;

  f32x4 accg[4] = {}; f32x4 accu[4] = {};

  for (int k0 = 0; k0 < HH; k0 += 64) {
    int kq = k0 >> 2;
    #pragma unroll
    for (int i = 0; i < 2; ++i)
      gload_lds16(xb + asrc[i] + k0, lA + (wave * 16 + i * 8) * 64);
    {
      float4 ga = bgp[kq], gb = bgp[kq + 1];
      lds_store16(lBg, brow, bc8, cvt8(ga, gb));
      float4 ua = bup[kq], ub = bup[kq + 1];
      lds_store16(lBu, brow, bc8, cvt8(ua, ub));
    }
    __syncthreads();
    #pragma unroll
    for (int ks = 0; ks < 2; ++ks) {
      int kb = ks * 32 + ((lane >> 4) << 3);
      bf16x8 g = lds_frag(lBg, wcol * 16 + (lane & 15), kb);
      bf16x8 u = lds_frag(lBu, wcol * 16 + (lane & 15), kb);
      #pragma unroll
      for (int i = 0; i < 4; ++i) {
        bf16x8 a = lds_frag(lA, wr * 64 + i * 16 + (lane & 15), kb);
        accg[i] = mfma16(a, g, accg[i]);
        accu[i] = mfma16(a, u, accu[i]);
      }
    }
    __syncthreads();
  }

  #pragma unroll
  for (int i = 0; i < 4; ++i)
    #pragma unroll
    for (int r = 0; r < 4; ++r) {
      int rloc = wr * 64 + i * 16 + ((lane >> 4) << 2) + r;
      int grow = row0 + rloc;
      if (grow < cnt) {
        int col = n0 + wcol * 16 + (lane & 15);
        float gv = accg[i][r], uv = accu[i][r];
        float act = gv / (1.f + __expf(-gv)) * uv;
        inter[(size_t)(off + grow) * II + col] = f2bf(act);
      }
    }
}

// ---------------- kernel 6: grouped GEMM2, scatter-add into out ----------------
// 512 thr / 8 waves. BM=128 rows, BN=128 cols. Wave = 64 rows x 32 cols: acc 32 AGPR.
__global__ __launch_bounds__(512, 4) void k_gemm2(
    const unsigned short* __restrict__ inter, const float* __restrict__ dwn,
    const int* __restrict__ tok_list, const float* __restrict__ wt_list,
    const int* __restrict__ counts, const int* __restrict__ offsets,
    const int* __restrict__ tiles, float* __restrict__ out) {
  const int nt = tiles[0];
  if ((int)blockIdx.y >= nt) return;
  const int tv = tiles[1 + blockIdx.y];
  const int e = tv >> 16;
  const int row0 = tv & 0xffff;
  const int cnt = counts[e];
  const int off = offsets[e];
  const int h0 = blockIdx.x * 128;
  const int tid = threadIdx.x;
  const int lane = tid & 63;
  const int wave = tid >> 6;
  const int wr = wave >> 2;        // 0..1
  const int wc = wave & 3;         // 0..3

  __shared__ __align__(16) unsigned short lA[128 * 64];   // 16 KB
  __shared__ __align__(16) unsigned short lB[128 * 64];   // 16 KB
  __shared__ int toks[128];
  __shared__ float wts[128];

  if (tid < 128) {
    int r = row0 + tid;
    int rc = r < cnt ? r : cnt - 1;
    toks[tid] = tok_list[e * TT + rc];
    wts[tid] = (r < cnt) ? wt_list[e * TT + rc] : 0.f;
  }
  __syncthreads();

  size_t asrc[2];
  #pragma unroll
  for (int i = 0; i < 2; ++i) {
    int lrow = wave * 16 + i * 8 + (lane >> 3);
    int rr = row0 + lrow; rr = rr < cnt ? rr : cnt - 1;
    asrc[i] = (size_t)(off + rr) * II + (((lane & 7) ^ (lrow & 7)) * 8);
  }
  int brow[2], bc8[2];
  const float4* bp[2];
  #pragma unroll
  for (int s = 0; s < 2; ++s) {
    int idx = tid + s * 512;                    // 128 rows x 8 chunks = 1024
    brow[s] = idx >> 3; bc8[s] = idx & 7;
    bp[s] = reinterpret_cast<const float4*>(
        dwn + ((size_t)e * HH + h0 + brow[s]) * II) + bc8[s] * 2;
  }

  f32x4 acc[4][2] = {};

  for (int k0 = 0; k0 < II; k0 += 64) {
    int kq = k0 >> 2;
    #pragma unroll
    for (int i = 0; i < 2; ++i)
      gload_lds16(inter + asrc[i] + k0, lA + (wave * 16 + i * 8) * 64);
    #pragma unroll
    for (int s = 0; s < 2; ++s) {
      float4 a = bp[s][kq], b = bp[s][kq + 1];
      lds_store16(lB, brow[s], bc8[s], cvt8(a, b));
    }
    __syncthreads();
    #pragma unroll
    for (int ks = 0; ks < 2; ++ks) {
      int kb = ks * 32 + ((lane >> 4) << 3);
      bf16x8 b0 = lds_frag(lB, wc * 32 + (lane & 15), kb);
      bf16x8 b1 = lds_frag(lB, wc * 32 + 16 + (lane & 15), kb);
      #pragma unroll
      for (int i = 0; i < 4; ++i) {
        bf16x8 a = lds_frag(lA, wr * 64 + i * 16 + (lane & 15), kb);
        acc[i][0] = mfma16(a, b0, acc[i][0]);
        acc[i][1] = mfma16(a, b1, acc[i][1]);
      }
    }
    __syncthreads();
  }

  #pragma unroll
  for (int i = 0; i < 4; ++i)
    #pragma unroll
    for (int j = 0; j < 2; ++j)
      #pragma unroll
      for (int r = 0; r < 4; ++r) {
        int rloc = wr * 64 + i * 16 + ((lane >> 4) << 2) + r;
        int grow = row0 + rloc;
        if (grow < cnt) {
          int h = h0 + wc * 32 + j * 16 + (lane & 15);
          unsafeAtomicAdd(&out[(size_t)toks[rloc] * HH + h], acc[i][j][r] * wts[rloc]);
        }
      }
}

// ---------------- ws layout ----------------
// xb      : TT*HH bf16          =  8,388,608 B   @ 0
// zero_w  : TT f32              =     16,384 B   @ 8,388,608
// counts  : 32 i32              =        128 B   @ 8,404,992
// offsets : 33 i32 (pad 256)    =        256 B   @ 8,405,120
// tok_list: 32*TT i32           =    524,288 B   @ 8,405,376
// wt_list : 32*TT f32           =    524,288 B   @ 8,929,664
// logits  : TT*E_T f32          =    655,360 B   @ 9,453,952
// tiles   : 1+MAXTILES i32 (4K) =      4,096 B   @ 10,109,312
// inter   : 24576*II bf16       = 25,165,824 B   @ 10,113,408
// total ~= 35.3 MB

extern "C" void kernel_launch(void* const* d_in, const int* in_sizes, int n_in,
                              void* d_out, int out_size, void* d_ws, size_t ws_size,
                              hipStream_t stream) {
  const float* x    = (const float*)d_in[0];
  const float* wcls = (const float*)d_in[1];
  const float* bias = (const float*)d_in[2];
  const float* gup  = (const float*)d_in[3];
  const float* dwn  = (const float*)d_in[4];
  float* out = (float*)d_out;

  char* w = (char*)d_ws;
  unsigned short* xb    = (unsigned short*)(w + 0);
  float* zero_w         = (float*)(w + 8388608);
  int* counts           = (int*)(w + 8404992);
  int* offsets          = (int*)(w + 8405120);
  int* tok_list         = (int*)(w + 8405376);
  float* wt_list        = (float*)(w + 8929664);
  float* logits         = (float*)(w + 9453952);
  int* tiles            = (int*)(w + 10109312);
  unsigned short* inter = (unsigned short*)(w + 10113408);

  hipMemsetAsync(counts, 0, E_R * sizeof(int), stream);
  k_convert_x<<<2048, 256, 0, stream>>>(x, xb);
  k_logits<<<1024, 256, 0, stream>>>(x, wcls, logits);
  k_topk<<<64, 64, 0, stream>>>(logits, bias, zero_w, counts, tok_list, wt_list);
  k_scan<<<1, 64, 0, stream>>>(counts, offsets, tiles);
  k_init_out<<<4096, 256, 0, stream>>>(x, zero_w, out);
  k_gemm1<<<dim3(8, MAXTILES), 512, 0, stream>>>(xb, gup, tok_list, counts, offsets, tiles, inter);
  k_gemm2<<<dim3(8, MAXTILES), 512, 0, stream>>>(inter, dwn, tok_list, wt_list, counts, offsets, tiles, out);
}

// Round 5
// 254.157 us; speedup vs baseline: 1.2105x; 1.0102x over previous
//
#include <hip/hip_runtime.h>
#include <float.h>
#include <math.h>

// Problem constants
#define TT 4096          // tokens = B*S
#define HH 1024          // hidden
#define II 512           // expert ffn hidden
#define E_R 32
#define E_T 40
#define TOPK 6
#define SCALE_F 2.5f
#define MAXTILES 224     // >= sum_e ceil(cnt_e/128); (24576+32*127)/128 = 223.75

typedef __bf16 bf16x8 __attribute__((ext_vector_type(8)));
typedef float f32x4 __attribute__((ext_vector_type(4)));

__device__ inline unsigned short f2bf(float f) {
  __bf16 h = (__bf16)f;
  return __builtin_bit_cast(unsigned short, h);
}

__device__ inline uint4 cvt8(float4 a, float4 b) {
  bf16x8 v;
  v[0] = (__bf16)a.x; v[1] = (__bf16)a.y; v[2] = (__bf16)a.z; v[3] = (__bf16)a.w;
  v[4] = (__bf16)b.x; v[5] = (__bf16)b.y; v[6] = (__bf16)b.z; v[7] = (__bf16)b.w;
  return __builtin_bit_cast(uint4, v);
}

// async global->LDS, 16B per lane, wave-uniform LDS base (linear dest)
__device__ inline void gload_lds16(const void* g, void* l) {
  __builtin_amdgcn_global_load_lds(
      (__attribute__((address_space(1))) void*)g,
      (__attribute__((address_space(3))) void*)l, 16, 0, 0);
}

// LDS tile: [rows][64 bf16], row stride 128 B, XOR swizzle byte^=((row&7)<<4).
// gload_lds path: LDS stays linear, SOURCE chunk is pre-XORed; read applies same XOR.
__device__ inline void lds_store16(unsigned short* base, int row, int c8, uint4 v) {
  int byte = (row * 128 + c8 * 16) ^ ((row & 7) << 4);
  *reinterpret_cast<uint4*>(reinterpret_cast<char*>(base) + byte) = v;
}
__device__ inline bf16x8 lds_frag(const unsigned short* base, int row, int kb) {
  int byte = (row * 128 + kb * 2) ^ ((row & 7) << 4);
  uint4 v = *reinterpret_cast<const uint4*>(reinterpret_cast<const char*>(base) + byte);
  return __builtin_bit_cast(bf16x8, v);
}

__device__ inline f32x4 mfma16(bf16x8 a, bf16x8 b, f32x4 c) {
  return __builtin_amdgcn_mfma_f32_16x16x32_bf16(a, b, c, 0, 0, 0);
}

// ---------------- kernel 1: convert x fp32 -> bf16 ----------------
__global__ void k_convert_x(const float* __restrict__ x, unsigned short* __restrict__ xb) {
  int i = blockIdx.x * 256 + threadIdx.x;
  const float4* p = reinterpret_cast<const float4*>(x) + (size_t)i * 2;
  float4 a = p[0], b = p[1];
  reinterpret_cast<uint4*>(xb)[i] = cvt8(a, b);
}

// ---------------- kernel 2a: router logits (fp32 GEMV, wave per token) ----------------
__global__ __launch_bounds__(256) void k_logits(const float* __restrict__ x,
                                                const float* __restrict__ wcls,
                                                float* __restrict__ logits) {
  __shared__ float4 ws4[E_T * 64];                 // 40 KB
  const int tid = threadIdx.x;
  const int lane = tid & 63;
  const int wave = tid >> 6;
  const int token = blockIdx.x * 4 + wave;
  const float4* x4 = reinterpret_cast<const float4*>(x);
  const float4* w4 = reinterpret_cast<const float4*>(wcls);

  float acc[E_T];
  #pragma unroll
  for (int e = 0; e < E_T; ++e) acc[e] = 0.f;

  for (int c = 0; c < 4; ++c) {
    if (c) __syncthreads();
    #pragma unroll
    for (int j = 0; j < 10; ++j) {
      int v = tid + j * 256;
      int e = v >> 6, kq = v & 63;
      ws4[v] = w4[e * 256 + c * 64 + kq];
    }
    float4 xv = x4[(size_t)token * 256 + c * 64 + lane];
    __syncthreads();
    #pragma unroll
    for (int e = 0; e < E_T; ++e) {
      float4 w = ws4[e * 64 + lane];
      acc[e] += xv.x * w.x + xv.y * w.y + xv.z * w.z + xv.w * w.w;
    }
  }

  float mine = 0.f;
  #pragma unroll
  for (int e = 0; e < E_T; ++e) {
    float r = acc[e];
    #pragma unroll
    for (int o = 32; o; o >>= 1) r += __shfl_xor(r, o);
    if (lane == e) mine = r;
  }
  if (lane < E_T) logits[(size_t)token * E_T + lane] = mine;
}

// ---------------- kernel 2b: softmax + top-k, one thread per token ----------------
__global__ void k_topk(const float* __restrict__ logits, const float* __restrict__ bias,
                       float* __restrict__ zero_w, int* __restrict__ counts,
                       int* __restrict__ tok_list,
                       int* __restrict__ route_ep, float* __restrict__ route_w,
                       int* __restrict__ route_n) {
  int t = blockIdx.x * 64 + threadIdx.x;
  float l[E_T];
  const float4* lp = reinterpret_cast<const float4*>(logits + (size_t)t * E_T);
  #pragma unroll
  for (int j = 0; j < E_T / 4; ++j) {
    float4 v = lp[j];
    l[j * 4 + 0] = v.x; l[j * 4 + 1] = v.y; l[j * 4 + 2] = v.z; l[j * 4 + 3] = v.w;
  }
  float m = -FLT_MAX;
  #pragma unroll
  for (int e = 0; e < E_T; ++e) m = fmaxf(m, l[e]);
  float den = 0.f;
  #pragma unroll
  for (int e = 0; e < E_T; ++e) { l[e] = __expf(l[e] - m); den += l[e]; }
  float inv = 1.f / den;
  float sel[E_T];
  #pragma unroll
  for (int e = 0; e < E_T; ++e) { l[e] *= inv; sel[e] = l[e] + bias[e]; }

  unsigned long long used = 0ull;
  float zw = 0.f;
  int nr = 0;
  for (int k = 0; k < TOPK; ++k) {
    float bv = -FLT_MAX; int bj = 0;
    #pragma unroll
    for (int e = 0; e < E_T; ++e) {
      float v = ((used >> e) & 1ull) ? -FLT_MAX : sel[e];
      if (v > bv) { bv = v; bj = e; }
    }
    used |= 1ull << bj;
    float wgt = (bv - bias[bj]) * SCALE_F;
    if (bj >= E_R) {
      zw += wgt;
    } else {
      int p = atomicAdd(&counts[bj], 1);
      tok_list[bj * TT + p] = t;
      route_ep[t * TOPK + nr] = (bj << 16) | p;
      route_w[t * TOPK + nr] = wgt;
      nr++;
    }
  }
  zero_w[t] = zw;
  route_n[t] = nr;
}

// ---------------- kernel 3: prefix scan + compact tile list ----------------
__global__ void k_scan(const int* __restrict__ counts, int* __restrict__ offsets,
                       int* __restrict__ tiles) {
  if (threadIdx.x == 0) {
    int s = 0, idx = 0;
    for (int e = 0; e < E_R; ++e) {
      offsets[e] = s;
      int c = counts[e];
      s += c;
      for (int r0 = 0; r0 < c; r0 += 128) tiles[1 + idx++] = (e << 16) | r0;
    }
    offsets[E_R] = s;
    tiles[0] = idx;
  }
}

// ---------------- kernel 5: grouped GEMM1 + SiLU*up -> inter (bf16) ----------------
// 512 thr / 8 waves. BM=128 rows, 64 gate + 64 up cols. Wave = 64 rows x (16g+16u).
// 2-phase double-buffer: STAGE(t+1) issued before compute(t), one barrier per K-step.
__global__ __launch_bounds__(512, 4) void k_gemm1(
    const unsigned short* __restrict__ xb, const float* __restrict__ gup,
    const int* __restrict__ tok_list, const int* __restrict__ counts,
    const int* __restrict__ offsets, const int* __restrict__ tiles,
    unsigned short* __restrict__ inter) {
  const int nt = tiles[0];
  if ((int)blockIdx.y >= nt) return;
  const int tv = tiles[1 + blockIdx.y];
  const int e = tv >> 16;
  const int row0 = tv & 0xffff;
  const int cnt = counts[e];
  const int off = offsets[e];
  const int n0 = blockIdx.x * 64;
  const int tid = threadIdx.x;
  const int lane = tid & 63;
  const int wave = tid >> 6;       // 0..7
  const int wr = wave >> 2;        // 0..1  M half
  const int wcol = wave & 3;       // 0..3  16-col slice

  __shared__ __align__(16) unsigned short lA0[128 * 64], lA1[128 * 64];   // 16 KB x2
  __shared__ __align__(16) unsigned short lBg0[64 * 64], lBg1[64 * 64];   // 8 KB x2
  __shared__ __align__(16) unsigned short lBu0[64 * 64], lBu1[64 * 64];   // 8 KB x2
  __shared__ int toks[128];

  if (tid < 128) {
    int r = row0 + tid;
    toks[tid] = tok_list[e * TT + (r < cnt ? r : cnt - 1)];
  }
  __syncthreads();

  size_t asrc[2];
  #pragma unroll
  for (int i = 0; i < 2; ++i) {
    int lrow = wave * 16 + i * 8 + (lane >> 3);
    asrc[i] = (size_t)toks[lrow] * HH + (((lane & 7) ^ (lrow & 7)) * 8);
  }
  const int brow = tid >> 3, bc8 = tid & 7;      // 512 thr = 64 rows x 8 chunks
  const float4* bgp = reinterpret_cast<const float4*>(
      gup + ((size_t)e * 1024 + n0 + brow) * HH) + bc8 * 2;
  const float4* bup = reinterpret_cast<const float4*>(
      gup + ((size_t)e * 1024 + 512 + n0 + brow) * HH) + bc8 * 2;

  f32x4 accg[4] = {}; f32x4 accu[4] = {};

  // prologue: stage tile 0 into buffer 0
  {
    #pragma unroll
    for (int i = 0; i < 2; ++i)
      gload_lds16(xb + asrc[i], lA0 + (wave * 16 + i * 8) * 64);
    float4 ga = bgp[0], gb = bgp[1], ua = bup[0], ub = bup[1];
    lds_store16(lBg0, brow, bc8, cvt8(ga, gb));
    lds_store16(lBu0, brow, bc8, cvt8(ua, ub));
  }
  __syncthreads();

  for (int t = 0; t < 16; ++t) {
    const bool last = (t == 15);
    unsigned short* cA  = (t & 1) ? lA1 : lA0;
    unsigned short* cBg = (t & 1) ? lBg1 : lBg0;
    unsigned short* cBu = (t & 1) ? lBu1 : lBu0;
    unsigned short* nA  = (t & 1) ? lA0 : lA1;
    unsigned short* nBg = (t & 1) ? lBg0 : lBg1;
    unsigned short* nBu = (t & 1) ? lBu0 : lBu1;

    float4 ga, gb, ua, ub;
    if (!last) {
      int k1 = (t + 1) * 64, kq = k1 >> 2;
      #pragma unroll
      for (int i = 0; i < 2; ++i)
        gload_lds16(xb + asrc[i] + k1, nA + (wave * 16 + i * 8) * 64);
      ga = bgp[kq]; gb = bgp[kq + 1]; ua = bup[kq]; ub = bup[kq + 1];
    }

    #pragma unroll
    for (int ks = 0; ks < 2; ++ks) {
      int kb = ks * 32 + ((lane >> 4) << 3);
      bf16x8 g = lds_frag(cBg, wcol * 16 + (lane & 15), kb);
      bf16x8 u = lds_frag(cBu, wcol * 16 + (lane & 15), kb);
      #pragma unroll
      for (int i = 0; i < 4; ++i) {
        bf16x8 a = lds_frag(cA, wr * 64 + i * 16 + (lane & 15), kb);
        accg[i] = mfma16(a, g, accg[i]);
        accu[i] = mfma16(a, u, accu[i]);
      }
    }

    if (!last) {
      lds_store16(nBg, brow, bc8, cvt8(ga, gb));
      lds_store16(nBu, brow, bc8, cvt8(ua, ub));
    }
    __syncthreads();
  }

  #pragma unroll
  for (int i = 0; i < 4; ++i)
    #pragma unroll
    for (int r = 0; r < 4; ++r) {
      int rloc = wr * 64 + i * 16 + ((lane >> 4) << 2) + r;
      int grow = row0 + rloc;
      if (grow < cnt) {
        int col = n0 + wcol * 16 + (lane & 15);
        float gv = accg[i][r], uv = accu[i][r];
        float act = gv / (1.f + __expf(-gv)) * uv;
        inter[(size_t)(off + grow) * II + col] = f2bf(act);
      }
    }
}

// ---------------- kernel 6: grouped GEMM2 -> inter2 rows (bf16, no atomics) ----------------
// 512 thr / 8 waves. BM=128 rows, BN=128 cols. Wave = 64 rows x 32 cols. 2-phase dbuf.
__global__ __launch_bounds__(512, 4) void k_gemm2(
    const unsigned short* __restrict__ inter, const float* __restrict__ dwn,
    const int* __restrict__ counts, const int* __restrict__ offsets,
    const int* __restrict__ tiles, unsigned short* __restrict__ inter2) {
  const int nt = tiles[0];
  if ((int)blockIdx.y >= nt) return;
  const int tv = tiles[1 + blockIdx.y];
  const int e = tv >> 16;
  const int row0 = tv & 0xffff;
  const int cnt = counts[e];
  const int off = offsets[e];
  const int h0 = blockIdx.x * 128;
  const int tid = threadIdx.x;
  const int lane = tid & 63;
  const int wave = tid >> 6;
  const int wr = wave >> 2;        // 0..1
  const int wc = wave & 3;         // 0..3

  __shared__ __align__(16) unsigned short lA0[128 * 64], lA1[128 * 64];   // 16 KB x2
  __shared__ __align__(16) unsigned short lB0[128 * 64], lB1[128 * 64];   // 16 KB x2

  size_t asrc[2];
  #pragma unroll
  for (int i = 0; i < 2; ++i) {
    int lrow = wave * 16 + i * 8 + (lane >> 3);
    int rr = row0 + lrow; rr = rr < cnt ? rr : cnt - 1;
    asrc[i] = (size_t)(off + rr) * II + (((lane & 7) ^ (lrow & 7)) * 8);
  }
  int brow[2], bc8[2];
  const float4* bp[2];
  #pragma unroll
  for (int s = 0; s < 2; ++s) {
    int idx = tid + s * 512;                    // 128 rows x 8 chunks = 1024
    brow[s] = idx >> 3; bc8[s] = idx & 7;
    bp[s] = reinterpret_cast<const float4*>(
        dwn + ((size_t)e * HH + h0 + brow[s]) * II) + bc8[s] * 2;
  }

  f32x4 acc[4][2] = {};

  // prologue: stage tile 0
  {
    #pragma unroll
    for (int i = 0; i < 2; ++i)
      gload_lds16(inter + asrc[i], lA0 + (wave * 16 + i * 8) * 64);
    #pragma unroll
    for (int s = 0; s < 2; ++s) {
      float4 a = bp[s][0], b = bp[s][1];
      lds_store16(lB0, brow[s], bc8[s], cvt8(a, b));
    }
  }
  __syncthreads();

  for (int t = 0; t < 8; ++t) {
    const bool last = (t == 7);
    unsigned short* cA = (t & 1) ? lA1 : lA0;
    unsigned short* cB = (t & 1) ? lB1 : lB0;
    unsigned short* nA = (t & 1) ? lA0 : lA1;
    unsigned short* nB = (t & 1) ? lB0 : lB1;

    float4 pa[2], pb[2];
    if (!last) {
      int k1 = (t + 1) * 64, kq = k1 >> 2;
      #pragma unroll
      for (int i = 0; i < 2; ++i)
        gload_lds16(inter + asrc[i] + k1, nA + (wave * 16 + i * 8) * 64);
      #pragma unroll
      for (int s = 0; s < 2; ++s) { pa[s] = bp[s][kq]; pb[s] = bp[s][kq + 1]; }
    }

    #pragma unroll
    for (int ks = 0; ks < 2; ++ks) {
      int kb = ks * 32 + ((lane >> 4) << 3);
      bf16x8 b0 = lds_frag(cB, wc * 32 + (lane & 15), kb);
      bf16x8 b1 = lds_frag(cB, wc * 32 + 16 + (lane & 15), kb);
      #pragma unroll
      for (int i = 0; i < 4; ++i) {
        bf16x8 a = lds_frag(cA, wr * 64 + i * 16 + (lane & 15), kb);
        acc[i][0] = mfma16(a, b0, acc[i][0]);
        acc[i][1] = mfma16(a, b1, acc[i][1]);
      }
    }

    if (!last) {
      #pragma unroll
      for (int s = 0; s < 2; ++s)
        lds_store16(nB, brow[s], bc8[s], cvt8(pa[s], pb[s]));
    }
    __syncthreads();
  }

  #pragma unroll
  for (int i = 0; i < 4; ++i)
    #pragma unroll
    for (int j = 0; j < 2; ++j)
      #pragma unroll
      for (int r = 0; r < 4; ++r) {
        int rloc = wr * 64 + i * 16 + ((lane >> 4) << 2) + r;
        int grow = row0 + rloc;
        if (grow < cnt) {
          int h = h0 + wc * 32 + j * 16 + (lane & 15);
          inter2[(size_t)(off + grow) * HH + h] = f2bf(acc[i][j][r]);
        }
      }
}

// ---------------- kernel 7: combine  out = zw*x + sum_k w_k * y_k ----------------
__global__ __launch_bounds__(256) void k_combine(
    const float* __restrict__ x, const float* __restrict__ zero_w,
    const int* __restrict__ offsets, const int* __restrict__ route_ep,
    const float* __restrict__ route_w, const int* __restrict__ route_n,
    const unsigned short* __restrict__ inter2, float* __restrict__ out) {
  const int t = blockIdx.x;
  const int tid = threadIdx.x;
  const float zw = zero_w[t];
  const int n = route_n[t];
  float4 o = reinterpret_cast<const float4*>(x)[t * 256 + tid];
  o.x *= zw; o.y *= zw; o.z *= zw; o.w *= zw;
  for (int i = 0; i < n; ++i) {
    int ep = route_ep[t * TOPK + i];
    int row = offsets[ep >> 16] + (ep & 0xffff);
    float w = route_w[t * TOPK + i];
    ushort4 v = reinterpret_cast<const ushort4*>(inter2 + (size_t)row * HH)[tid];
    o.x += w * __builtin_bit_cast(float, (unsigned)v.x << 16);
    o.y += w * __builtin_bit_cast(float, (unsigned)v.y << 16);
    o.z += w * __builtin_bit_cast(float, (unsigned)v.z << 16);
    o.w += w * __builtin_bit_cast(float, (unsigned)v.w << 16);
  }
  reinterpret_cast<float4*>(out)[t * 256 + tid] = o;
}

// ---------------- ws layout ----------------
// xb      : TT*HH bf16          =  8,388,608 B   @ 0
// zero_w  : TT f32              =     16,384 B   @ 8,388,608
// counts  : 32 i32              =        128 B   @ 8,404,992
// offsets : 33 i32 (pad 256)    =        256 B   @ 8,405,120
// tok_list: 32*TT i32           =    524,288 B   @ 8,405,376
// logits  : TT*E_T f32          =    655,360 B   @ 8,929,664
// tiles   : 1+MAXTILES i32      =      4,096 B   @ 9,585,024
// route_ep: TT*6 i32            =     98,304 B   @ 9,589,120
// route_w : TT*6 f32            =     98,304 B   @ 9,687,424
// route_n : TT i32              =     16,384 B   @ 9,785,728
// inter   : 24576*II bf16       = 25,165,824 B   @ 9,802,112
// inter2  : 24576*HH bf16       = 50,331,648 B   @ 34,967,936
// total ~= 85.3 MB

extern "C" void kernel_launch(void* const* d_in, const int* in_sizes, int n_in,
                              void* d_out, int out_size, void* d_ws, size_t ws_size,
                              hipStream_t stream) {
  const float* x    = (const float*)d_in[0];
  const float* wcls = (const float*)d_in[1];
  const float* bias = (const float*)d_in[2];
  const float* gup  = (const float*)d_in[3];
  const float* dwn  = (const float*)d_in[4];
  float* out = (float*)d_out;

  char* w = (char*)d_ws;
  unsigned short* xb    = (unsigned short*)(w + 0);
  float* zero_w         = (float*)(w + 8388608);
  int* counts           = (int*)(w + 8404992);
  int* offsets          = (int*)(w + 8405120);
  int* tok_list         = (int*)(w + 8405376);
  float* logits         = (float*)(w + 8929664);
  int* tiles            = (int*)(w + 9585024);
  int* route_ep         = (int*)(w + 9589120);
  float* route_w        = (float*)(w + 9687424);
  int* route_n          = (int*)(w + 9785728);
  unsigned short* inter = (unsigned short*)(w + 9802112);
  unsigned short* inter2 = (unsigned short*)(w + 34967936);

  hipMemsetAsync(counts, 0, E_R * sizeof(int), stream);
  k_convert_x<<<2048, 256, 0, stream>>>(x, xb);
  k_logits<<<1024, 256, 0, stream>>>(x, wcls, logits);
  k_topk<<<64, 64, 0, stream>>>(logits, bias, zero_w, counts, tok_list,
                                route_ep, route_w, route_n);
  k_scan<<<1, 64, 0, stream>>>(counts, offsets, tiles);
  k_gemm1<<<dim3(8, MAXTILES), 512, 0, stream>>>(xb, gup, tok_list, counts, offsets, tiles, inter);
  k_gemm2<<<dim3(8, MAXTILES), 512, 0, stream>>>(inter, dwn, counts, offsets, tiles, inter2);
  k_combine<<<TT, 256, 0, stream>>>(x, zero_w, offsets, route_ep, route_w, route_n,
                                    inter2, out);
}

// Round 6
// 231.102 us; speedup vs baseline: 1.3313x; 1.0998x over previous
//
#include <hip/hip_runtime.h>
#include <float.h>
#include <math.h>

// Problem constants
#define TT 4096          // tokens = B*S
#define HH 1024          // hidden
#define II 512           // expert ffn hidden
#define E_R 32
#define E_T 40
#define TOPK 6
#define SCALE_F 2.5f
#define MAXTILES 224     // >= sum_e ceil(cnt_e/128); (24576+32*127)/128 = 223.75

typedef __bf16 bf16x8 __attribute__((ext_vector_type(8)));
typedef float f32x4 __attribute__((ext_vector_type(4)));

__device__ inline unsigned short f2bf(float f) {
  __bf16 h = (__bf16)f;
  return __builtin_bit_cast(unsigned short, h);
}

__device__ inline uint4 cvt8(float4 a, float4 b) {
  bf16x8 v;
  v[0] = (__bf16)a.x; v[1] = (__bf16)a.y; v[2] = (__bf16)a.z; v[3] = (__bf16)a.w;
  v[4] = (__bf16)b.x; v[5] = (__bf16)b.y; v[6] = (__bf16)b.z; v[7] = (__bf16)b.w;
  return __builtin_bit_cast(uint4, v);
}

// async global->LDS, 16B per lane, wave-uniform LDS base (linear dest)
__device__ inline void gload_lds16(const void* g, void* l) {
  __builtin_amdgcn_global_load_lds(
      (__attribute__((address_space(1))) void*)g,
      (__attribute__((address_space(3))) void*)l, 16, 0, 0);
}

// LDS tile: [rows][64 bf16], row stride 128 B, XOR swizzle byte^=((row&7)<<4).
// gload_lds path: LDS stays linear, SOURCE chunk is pre-XORed; read applies same XOR.
__device__ inline void lds_store16(unsigned short* base, int row, int c8, uint4 v) {
  int byte = (row * 128 + c8 * 16) ^ ((row & 7) << 4);
  *reinterpret_cast<uint4*>(reinterpret_cast<char*>(base) + byte) = v;
}
__device__ inline bf16x8 lds_frag(const unsigned short* base, int row, int kb) {
  int byte = (row * 128 + kb * 2) ^ ((row & 7) << 4);
  uint4 v = *reinterpret_cast<const uint4*>(reinterpret_cast<const char*>(base) + byte);
  return __builtin_bit_cast(bf16x8, v);
}

__device__ inline f32x4 mfma16(bf16x8 a, bf16x8 b, f32x4 c) {
  return __builtin_amdgcn_mfma_f32_16x16x32_bf16(a, b, c, 0, 0, 0);
}

// ---------------- kernel 1: convert x fp32 -> bf16 ----------------
__global__ void k_convert_x(const float* __restrict__ x, unsigned short* __restrict__ xb) {
  int i = blockIdx.x * 256 + threadIdx.x;
  const float4* p = reinterpret_cast<const float4*>(x) + (size_t)i * 2;
  float4 a = p[0], b = p[1];
  reinterpret_cast<uint4*>(xb)[i] = cvt8(a, b);
}

// ---------------- kernel 2a: router logits (fp32 GEMV, wave per token) ----------------
__global__ __launch_bounds__(256) void k_logits(const float* __restrict__ x,
                                                const float* __restrict__ wcls,
                                                float* __restrict__ logits) {
  __shared__ float4 ws4[E_T * 64];                 // 40 KB
  const int tid = threadIdx.x;
  const int lane = tid & 63;
  const int wave = tid >> 6;
  const int token = blockIdx.x * 4 + wave;
  const float4* x4 = reinterpret_cast<const float4*>(x);
  const float4* w4 = reinterpret_cast<const float4*>(wcls);

  float acc[E_T];
  #pragma unroll
  for (int e = 0; e < E_T; ++e) acc[e] = 0.f;

  for (int c = 0; c < 4; ++c) {
    if (c) __syncthreads();
    #pragma unroll
    for (int j = 0; j < 10; ++j) {
      int v = tid + j * 256;
      int e = v >> 6, kq = v & 63;
      ws4[v] = w4[e * 256 + c * 64 + kq];
    }
    float4 xv = x4[(size_t)token * 256 + c * 64 + lane];
    __syncthreads();
    #pragma unroll
    for (int e = 0; e < E_T; ++e) {
      float4 w = ws4[e * 64 + lane];
      acc[e] += xv.x * w.x + xv.y * w.y + xv.z * w.z + xv.w * w.w;
    }
  }

  float mine = 0.f;
  #pragma unroll
  for (int e = 0; e < E_T; ++e) {
    float r = acc[e];
    #pragma unroll
    for (int o = 32; o; o >>= 1) r += __shfl_xor(r, o);
    if (lane == e) mine = r;
  }
  if (lane < E_T) logits[(size_t)token * E_T + lane] = mine;
}

// ---------------- kernel 2b: softmax + top-k, one thread per token ----------------
__global__ void k_topk(const float* __restrict__ logits, const float* __restrict__ bias,
                       float* __restrict__ zero_w, int* __restrict__ counts,
                       int* __restrict__ tok_list,
                       int* __restrict__ route_ep, float* __restrict__ route_w,
                       int* __restrict__ route_n) {
  int t = blockIdx.x * 64 + threadIdx.x;
  float l[E_T];
  const float4* lp = reinterpret_cast<const float4*>(logits + (size_t)t * E_T);
  #pragma unroll
  for (int j = 0; j < E_T / 4; ++j) {
    float4 v = lp[j];
    l[j * 4 + 0] = v.x; l[j * 4 + 1] = v.y; l[j * 4 + 2] = v.z; l[j * 4 + 3] = v.w;
  }
  float m = -FLT_MAX;
  #pragma unroll
  for (int e = 0; e < E_T; ++e) m = fmaxf(m, l[e]);
  float den = 0.f;
  #pragma unroll
  for (int e = 0; e < E_T; ++e) { l[e] = __expf(l[e] - m); den += l[e]; }
  float inv = 1.f / den;
  float sel[E_T];
  #pragma unroll
  for (int e = 0; e < E_T; ++e) { l[e] *= inv; sel[e] = l[e] + bias[e]; }

  unsigned long long used = 0ull;
  float zw = 0.f;
  int nr = 0;
  for (int k = 0; k < TOPK; ++k) {
    float bv = -FLT_MAX; int bj = 0;
    #pragma unroll
    for (int e = 0; e < E_T; ++e) {
      float v = ((used >> e) & 1ull) ? -FLT_MAX : sel[e];
      if (v > bv) { bv = v; bj = e; }
    }
    used |= 1ull << bj;
    float wgt = (bv - bias[bj]) * SCALE_F;
    if (bj >= E_R) {
      zw += wgt;
    } else {
      int p = atomicAdd(&counts[bj], 1);
      tok_list[bj * TT + p] = t;
      route_ep[t * TOPK + nr] = (bj << 16) | p;
      route_w[t * TOPK + nr] = wgt;
      nr++;
    }
  }
  zero_w[t] = zw;
  route_n[t] = nr;
}

// ---------------- kernel 3: prefix scan + compact tile list ----------------
__global__ void k_scan(const int* __restrict__ counts, int* __restrict__ offsets,
                       int* __restrict__ tiles) {
  if (threadIdx.x == 0) {
    int s = 0, idx = 0;
    for (int e = 0; e < E_R; ++e) {
      offsets[e] = s;
      int c = counts[e];
      s += c;
      for (int r0 = 0; r0 < c; r0 += 128) tiles[1 + idx++] = (e << 16) | r0;
    }
    offsets[E_R] = s;
    tiles[0] = idx;
  }
}

// ---------------- kernel 5: grouped GEMM1 + SiLU*up -> inter (bf16) ----------------
// m97 geometry: 256 thr / 4 waves (2x2), block = 128 rows x (64 gate + 64 up cols),
// wave = 64 rows x (32 g + 32 u), acc 16 f32x4 = 64 AGPR. Single-buffered LDS 32KB.
__global__ __launch_bounds__(256, 3) void k_gemm1(
    const unsigned short* __restrict__ xb, const float* __restrict__ gup,
    const int* __restrict__ tok_list, const int* __restrict__ counts,
    const int* __restrict__ offsets, const int* __restrict__ tiles,
    unsigned short* __restrict__ inter) {
  const int nt = tiles[0];
  if ((int)blockIdx.y >= nt) return;
  const int tv = tiles[1 + blockIdx.y];
  const int e = tv >> 16;
  const int row0 = tv & 0xffff;
  const int cnt = counts[e];
  const int off = offsets[e];
  const int n0 = blockIdx.x * 64;
  const int tid = threadIdx.x;
  const int lane = tid & 63;
  const int wave = tid >> 6;       // 0..3
  const int wr = wave >> 1;        // 0..1 row half
  const int wc = wave & 1;         // 0..1 col half (32 of 64)

  __shared__ __align__(16) unsigned short lA[128 * 64];   // 16 KB
  __shared__ __align__(16) unsigned short lBg[64 * 64];   // 8 KB
  __shared__ __align__(16) unsigned short lBu[64 * 64];   // 8 KB
  __shared__ int toks[128];

  if (tid < 128) {
    int r = row0 + tid;
    toks[tid] = tok_list[e * TT + (r < cnt ? r : cnt - 1)];
  }
  __syncthreads();

  // A staging: 4 gload_lds issues per wave (8 rows each), pre-swizzled source
  size_t asrc[4];
  #pragma unroll
  for (int i = 0; i < 4; ++i) {
    int lrow = wave * 32 + i * 8 + (lane >> 3);
    asrc[i] = (size_t)toks[lrow] * HH + (((lane & 7) ^ (lrow & 7)) * 8);
  }
  // B staging: Bg 512 chunk-stores + Bu 512 over 256 threads -> 2 each
  int brow[2], bc8[2];
  const float4* bgp[2]; const float4* bup[2];
  #pragma unroll
  for (int s = 0; s < 2; ++s) {
    int idx = tid + s * 256;
    brow[s] = idx >> 3; bc8[s] = idx & 7;
    bgp[s] = reinterpret_cast<const float4*>(
        gup + ((size_t)e * 1024 + n0 + brow[s]) * HH) + bc8[s] * 2;
    bup[s] = reinterpret_cast<const float4*>(
        gup + ((size_t)e * 1024 + 512 + n0 + brow[s]) * HH) + bc8[s] * 2;
  }

  f32x4 accg[4][2] = {}; f32x4 accu[4][2] = {};

  for (int k0 = 0; k0 < HH; k0 += 64) {
    int kq = k0 >> 2;
    #pragma unroll
    for (int i = 0; i < 4; ++i)
      gload_lds16(xb + asrc[i] + k0, lA + (wave * 32 + i * 8) * 64);
    #pragma unroll
    for (int s = 0; s < 2; ++s) {
      float4 ga = bgp[s][kq], gb = bgp[s][kq + 1];
      lds_store16(lBg, brow[s], bc8[s], cvt8(ga, gb));
      float4 ua = bup[s][kq], ub = bup[s][kq + 1];
      lds_store16(lBu, brow[s], bc8[s], cvt8(ua, ub));
    }
    __syncthreads();
    #pragma unroll
    for (int ks = 0; ks < 2; ++ks) {
      int kb = ks * 32 + ((lane >> 4) << 3);
      bf16x8 a[4], g[2], u[2];
      #pragma unroll
      for (int i = 0; i < 4; ++i) a[i] = lds_frag(lA, wr * 64 + i * 16 + (lane & 15), kb);
      #pragma unroll
      for (int j = 0; j < 2; ++j) {
        g[j] = lds_frag(lBg, wc * 32 + j * 16 + (lane & 15), kb);
        u[j] = lds_frag(lBu, wc * 32 + j * 16 + (lane & 15), kb);
      }
      #pragma unroll
      for (int i = 0; i < 4; ++i)
        #pragma unroll
        for (int j = 0; j < 2; ++j) {
          accg[i][j] = mfma16(a[i], g[j], accg[i][j]);
          accu[i][j] = mfma16(a[i], u[j], accu[i][j]);
        }
    }
    __syncthreads();
  }

  #pragma unroll
  for (int i = 0; i < 4; ++i)
    #pragma unroll
    for (int j = 0; j < 2; ++j)
      #pragma unroll
      for (int r = 0; r < 4; ++r) {
        int rloc = wr * 64 + i * 16 + ((lane >> 4) << 2) + r;
        int grow = row0 + rloc;
        if (grow < cnt) {
          int col = n0 + wc * 32 + j * 16 + (lane & 15);
          float gv = accg[i][j][r], uv = accu[i][j][r];
          float act = gv / (1.f + __expf(-gv)) * uv;
          inter[(size_t)(off + grow) * II + col] = f2bf(act);
        }
      }
}

// ---------------- kernel 6: grouped GEMM2 -> inter2 rows (bf16, no atomics) ----------------
// 256 thr / 4 waves (2x2), block = 128 rows x 128 cols, wave 64x64, acc 4x4.
__global__ __launch_bounds__(256, 3) void k_gemm2(
    const unsigned short* __restrict__ inter, const float* __restrict__ dwn,
    const int* __restrict__ counts, const int* __restrict__ offsets,
    const int* __restrict__ tiles, unsigned short* __restrict__ inter2) {
  const int nt = tiles[0];
  if ((int)blockIdx.y >= nt) return;
  const int tv = tiles[1 + blockIdx.y];
  const int e = tv >> 16;
  const int row0 = tv & 0xffff;
  const int cnt = counts[e];
  const int off = offsets[e];
  const int h0 = blockIdx.x * 128;
  const int tid = threadIdx.x;
  const int lane = tid & 63;
  const int wave = tid >> 6;
  const int wr = wave >> 1;        // 0..1
  const int wc = wave & 1;         // 0..1

  __shared__ __align__(16) unsigned short lA[128 * 64];   // 16 KB
  __shared__ __align__(16) unsigned short lB[128 * 64];   // 16 KB

  size_t asrc[4];
  #pragma unroll
  for (int i = 0; i < 4; ++i) {
    int lrow = wave * 32 + i * 8 + (lane >> 3);
    int rr = row0 + lrow; rr = rr < cnt ? rr : cnt - 1;
    asrc[i] = (size_t)(off + rr) * II + (((lane & 7) ^ (lrow & 7)) * 8);
  }
  int brow[4], bc8[4];
  const float4* bp[4];
  #pragma unroll
  for (int s = 0; s < 4; ++s) {
    int idx = tid + s * 256;                    // 128 rows x 8 chunks = 1024
    brow[s] = idx >> 3; bc8[s] = idx & 7;
    bp[s] = reinterpret_cast<const float4*>(
        dwn + ((size_t)e * HH + h0 + brow[s]) * II) + bc8[s] * 2;
  }

  f32x4 acc[4][4] = {};

  for (int k0 = 0; k0 < II; k0 += 64) {
    int kq = k0 >> 2;
    #pragma unroll
    for (int i = 0; i < 4; ++i)
      gload_lds16(inter + asrc[i] + k0, lA + (wave * 32 + i * 8) * 64);
    #pragma unroll
    for (int s = 0; s < 4; ++s) {
      float4 a = bp[s][kq], b = bp[s][kq + 1];
      lds_store16(lB, brow[s], bc8[s], cvt8(a, b));
    }
    __syncthreads();
    #pragma unroll
    for (int ks = 0; ks < 2; ++ks) {
      int kb = ks * 32 + ((lane >> 4) << 3);
      bf16x8 a[4], b[4];
      #pragma unroll
      for (int i = 0; i < 4; ++i) a[i] = lds_frag(lA, wr * 64 + i * 16 + (lane & 15), kb);
      #pragma unroll
      for (int j = 0; j < 4; ++j) b[j] = lds_frag(lB, wc * 64 + j * 16 + (lane & 15), kb);
      #pragma unroll
      for (int i = 0; i < 4; ++i)
        #pragma unroll
        for (int j = 0; j < 4; ++j)
          acc[i][j] = mfma16(a[i], b[j], acc[i][j]);
    }
    __syncthreads();
  }

  #pragma unroll
  for (int i = 0; i < 4; ++i)
    #pragma unroll
    for (int j = 0; j < 4; ++j)
      #pragma unroll
      for (int r = 0; r < 4; ++r) {
        int rloc = wr * 64 + i * 16 + ((lane >> 4) << 2) + r;
        int grow = row0 + rloc;
        if (grow < cnt) {
          int h = h0 + wc * 64 + j * 16 + (lane & 15);
          inter2[(size_t)(off + grow) * HH + h] = f2bf(acc[i][j][r]);
        }
      }
}

// ---------------- kernel 7: combine  out = zw*x + sum_k w_k * y_k ----------------
__global__ __launch_bounds__(256) void k_combine(
    const float* __restrict__ x, const float* __restrict__ zero_w,
    const int* __restrict__ offsets, const int* __restrict__ route_ep,
    const float* __restrict__ route_w, const int* __restrict__ route_n,
    const unsigned short* __restrict__ inter2, float* __restrict__ out) {
  const int t = blockIdx.x;
  const int tid = threadIdx.x;
  const float zw = zero_w[t];
  const int n = route_n[t];
  float4 o = reinterpret_cast<const float4*>(x)[t * 256 + tid];
  o.x *= zw; o.y *= zw; o.z *= zw; o.w *= zw;
  for (int i = 0; i < n; ++i) {
    int ep = route_ep[t * TOPK + i];
    int row = offsets[ep >> 16] + (ep & 0xffff);
    float w = route_w[t * TOPK + i];
    ushort4 v = reinterpret_cast<const ushort4*>(inter2 + (size_t)row * HH)[tid];
    o.x += w * __builtin_bit_cast(float, (unsigned)v.x << 16);
    o.y += w * __builtin_bit_cast(float, (unsigned)v.y << 16);
    o.z += w * __builtin_bit_cast(float, (unsigned)v.z << 16);
    o.w += w * __builtin_bit_cast(float, (unsigned)v.w << 16);
  }
  reinterpret_cast<float4*>(out)[t * 256 + tid] = o;
}

// ---------------- ws layout ----------------
// xb      : TT*HH bf16          =  8,388,608 B   @ 0
// zero_w  : TT f32              =     16,384 B   @ 8,388,608
// counts  : 32 i32              =        128 B   @ 8,404,992
// offsets : 33 i32 (pad 256)    =        256 B   @ 8,405,120
// tok_list: 32*TT i32           =    524,288 B   @ 8,405,376
// logits  : TT*E_T f32          =    655,360 B   @ 8,929,664
// tiles   : 1+MAXTILES i32      =      4,096 B   @ 9,585,024
// route_ep: TT*6 i32            =     98,304 B   @ 9,589,120
// route_w : TT*6 f32            =     98,304 B   @ 9,687,424
// route_n : TT i32              =     16,384 B   @ 9,785,728
// inter   : 24576*II bf16       = 25,165,824 B   @ 9,802,112
// inter2  : 24576*HH bf16       = 50,331,648 B   @ 34,967,936
// total ~= 85.3 MB

extern "C" void kernel_launch(void* const* d_in, const int* in_sizes, int n_in,
                              void* d_out, int out_size, void* d_ws, size_t ws_size,
                              hipStream_t stream) {
  const float* x    = (const float*)d_in[0];
  const float* wcls = (const float*)d_in[1];
  const float* bias = (const float*)d_in[2];
  const float* gup  = (const float*)d_in[3];
  const float* dwn  = (const float*)d_in[4];
  float* out = (float*)d_out;

  char* w = (char*)d_ws;
  unsigned short* xb    = (unsigned short*)(w + 0);
  float* zero_w         = (float*)(w + 8388608);
  int* counts           = (int*)(w + 8404992);
  int* offsets          = (int*)(w + 8405120);
  int* tok_list         = (int*)(w + 8405376);
  float* logits         = (float*)(w + 8929664);
  int* tiles            = (int*)(w + 9585024);
  int* route_ep         = (int*)(w + 9589120);
  float* route_w        = (float*)(w + 9687424);
  int* route_n          = (int*)(w + 9785728);
  unsigned short* inter = (unsigned short*)(w + 9802112);
  unsigned short* inter2 = (unsigned short*)(w + 34967936);

  hipMemsetAsync(counts, 0, E_R * sizeof(int), stream);
  k_convert_x<<<2048, 256, 0, stream>>>(x, xb);
  k_logits<<<1024, 256, 0, stream>>>(x, wcls, logits);
  k_topk<<<64, 64, 0, stream>>>(logits, bias, zero_w, counts, tok_list,
                                route_ep, route_w, route_n);
  k_scan<<<1, 64, 0, stream>>>(counts, offsets, tiles);
  k_gemm1<<<dim3(8, MAXTILES), 256, 0, stream>>>(xb, gup, tok_list, counts, offsets, tiles, inter);
  k_gemm2<<<dim3(8, MAXTILES), 256, 0, stream>>>(inter, dwn, counts, offsets, tiles, inter2);
  k_combine<<<TT, 256, 0, stream>>>(x, zero_w, offsets, route_ep, route_w, route_n,
                                    inter2, out);
}